// Round 8
// baseline (311.734 us; speedup 1.0000x reference)
//
#include <hip/hip_runtime.h>
#include <hip/hip_bf16.h>

// GroupQueryAttention: B=2,S=2048,E=768,H=12,G=4,D=64,T=512
// R16 = attn k-split with deferred normalization:
//   - attn: 4-wave/256-thr blocks, each wave 32 q-rows (2 subtiles, the
//     refcheck-passed R15 inner body => 2 MFMA per ds_read), block covers
//     128 q-rows x HALF the k-range (no-max softmax partials are additive).
//     grid = 96 heads x 4 qtiles x 2 khalves = 768 -> 12 waves/CU (R13
//     occupancy) AND ratio-2 amortization (R15 inner). Writes UNNORMALIZED
//     f32 partials P0/P1 + row-sums L0/L1; ctxB eliminated.
//   - out_gemm: A-staging reads P0+P1, scales by 1/(L0+L1) per 8-chunk
//     (h = e>>6 const per chunk), cvt to bf16 -> LDS. Epilogue unchanged.
//   - P0 aliases Wbf[0..6.29M shorts] (weights 0..10, dead after mid; Wout
//     at 15U=8.85M safe). P1 aliases q_proj+k_proj. L0/L1 alias v_proj.
//   mid/qkv/cast unchanged from R13 (best banked 289.8 us).

typedef __attribute__((ext_vector_type(8))) short short8;
typedef __attribute__((ext_vector_type(4))) float floatx4;
typedef __attribute__((ext_vector_type(4))) int intx4;

static __device__ __forceinline__ short f2bf(float f) {
    __bf16 b = (__bf16)f;              // fptrunc RNE -> HW cvt
    return __builtin_bit_cast(short, b);
}
static __device__ __forceinline__ short8 f8_to_bf8(floatx4 f0, floatx4 f1) {
    short8 s;
    s[0]=f2bf(f0[0]); s[1]=f2bf(f0[1]); s[2]=f2bf(f0[2]); s[3]=f2bf(f0[3]);
    s[4]=f2bf(f1[0]); s[5]=f2bf(f1[1]); s[6]=f2bf(f1[2]); s[7]=f2bf(f1[3]);
    return s;
}
static __device__ __forceinline__ unsigned cvt_pk_bf16(float a, float b) {
    unsigned r;                        // D[15:0]=bf16(a), D[31:16]=bf16(b)
    asm("v_cvt_pk_bf16_f32 %0, %1, %2" : "=v"(r) : "v"(a), "v"(b));
    return r;
}
static __device__ __forceinline__ void gload_lds16(const short* g, short* l) {
    __builtin_amdgcn_global_load_lds(
        (const __attribute__((address_space(1))) unsigned int*)g,
        (__attribute__((address_space(3))) unsigned int*)l, 16, 0, 0);
}

// ---------------------------------------------------------------------------
// weights fp32->bf16 (7 tensors, 19*768^2 elems contiguous dst)
// ---------------------------------------------------------------------------
__global__ __launch_bounds__(256) void cast_w(
    const float* a0, const float* a1, const float* a2, const float* a3,
    const float* a4, const float* a5, const float* a6, short* dst)
{
    const long U = 589824L;
    const float* ptrs[7] = {a0,a1,a2,a3,a4,a5,a6};
    const long starts[8] = {0, U, 2*U, 3*U, 7*U, 11*U, 15*U, 19*U};
    long i = (long)blockIdx.x * 2048 + (long)threadIdx.x * 8;
    int t = 0;
    while (t < 6 && i >= starts[t + 1]) t++;
    const float* s = ptrs[t] + (i - starts[t]);
    floatx4 f0 = *(const floatx4*)s;
    floatx4 f1 = *(const floatx4*)(s + 4);
    *(short8*)(dst + i) = f8_to_bf8(f0, f1);
}

// ---------------------------------------------------------------------------
// 128x128 MFMA core pieces. C/D layout: col=lane&15, row=quad*4+reg.
// ---------------------------------------------------------------------------
#define GEMM_LANE_VARS                                                        \
    const int tid = threadIdx.x, lane = tid & 63, w = tid >> 6;               \
    const int wm = w & 1, wn = w >> 1;                                        \
    const int qr = lane >> 4, lc = lane & 15, x7 = lc & 7;                    \
    const int srow = tid >> 3, schunk = tid & 7, sx = srow & 7;

template<int CMODE, int BIAS_MODE>
static __device__ __forceinline__ void gemm_epilogue(
    floatx4 (&acc)[4][4], const float* bp, void* Cv, int ldc, int bm, int bn,
    int wm, int wn, int qr, int lc)
{
#pragma unroll
    for (int ni = 0; ni < 4; ni++) {
        const int gcol = bn * 128 + wn * 64 + ni * 16 + lc;
        const float bcol = (BIAS_MODE == 0) ? bp[gcol] : 0.f;
#pragma unroll
        for (int mi = 0; mi < 4; mi++) {
#pragma unroll
            for (int r = 0; r < 4; r++) {
                const int grow = bm * 128 + wm * 64 + mi * 16 + qr * 4 + r;
                const float bb = (BIAS_MODE == 1) ? bp[grow] : bcol;
                const float v = acc[mi][ni][r] + bb;
                if (CMODE == 0)
                    ((short*)Cv)[(long)grow * ldc + gcol] = f2bf(v);
                else
                    ((float*)Cv)[(long)grow * ldc + gcol] = v;
            }
        }
    }
}

static __device__ __forceinline__ void gemm_mfma_step(
    floatx4 (&acc)[4][4], const short* Ac, const short* Bc,
    int wm, int wn, int qr, int lc, int x7)
{
#pragma unroll
    for (int ks = 0; ks < 64; ks += 32) {
        const int c0 = (ks >> 3) + qr;
        const int slot = ((c0 ^ x7) << 3);
        short8 af[4], bfr[4];
#pragma unroll
        for (int mi = 0; mi < 4; mi++)
            af[mi] = *(const short8*)&Ac[(wm * 64 + mi * 16 + lc) * 64 + slot];
#pragma unroll
        for (int ni = 0; ni < 4; ni++)
            bfr[ni] = *(const short8*)&Bc[(wn * 64 + ni * 16 + lc) * 64 + slot];
#pragma unroll
        for (int mi = 0; mi < 4; mi++)
#pragma unroll
            for (int ni = 0; ni < 4; ni++)
                acc[mi][ni] = __builtin_amdgcn_mfma_f32_16x16x32_bf16(
                    af[mi], bfr[ni], acc[mi][ni], 0, 0, 0);
    }
}

// ---------------------------------------------------------------------------
// Single-buffered core for fp32 A (qkv only).
// ---------------------------------------------------------------------------
template<int CMODE, int BIAS_MODE>
static __device__ __forceinline__ void gemm_core_f32(
    const float* __restrict__ A, const short* __restrict__ Wb,
    const float* __restrict__ bp, void* __restrict__ Cv,
    int lda, int ldc, int bm, int bn, short* As, short* Bs)
{
    GEMM_LANE_VARS
    const short* Wt = Wb + (long)(bn * 128) * 768;

    floatx4 acc[4][4];
#pragma unroll
    for (int mi = 0; mi < 4; mi++)
#pragma unroll
        for (int ni = 0; ni < 4; ni++) acc[mi][ni] = (floatx4){0.f, 0.f, 0.f, 0.f};

    for (int k0 = 0; k0 < 768; k0 += 64) {
        __syncthreads();
#pragma unroll
        for (int p = 0; p < 4; p++) {
            const int row = p * 32 + srow;
            const float* ap = A + (long)(bm * 128 + row) * lda + k0 + schunk * 8;
            floatx4 f0 = *(const floatx4*)ap;
            floatx4 f1 = *(const floatx4*)(ap + 4);
            *(short8*)&As[row * 64 + ((schunk ^ sx) << 3)] = f8_to_bf8(f0, f1);
            gload_lds16(Wt + (long)row * 768 + k0 + ((schunk ^ sx) << 3),
                        &Bs[(p * 32 + w * 8) * 64]);
        }
        __syncthreads();
        gemm_mfma_step(acc, As, Bs, wm, wn, qr, lc, x7);
    }
    gemm_epilogue<CMODE, BIAS_MODE>(acc, bp, Cv, ldc, bm, bn, wm, wn, qr, lc);
}

// qkv projections: grid (576). XCD k owns bm in [4k,4k+4); order bm->y->bn.
__global__ __launch_bounds__(256) void qkv_gemm(
    const float* q, const float* k, const float* v, const short* Wbf,
    const float* bq, const float* bk, const float* bv, short* outp)
{
    __shared__ short As[128 * 64];
    __shared__ short Bs[128 * 64];
    const int xcd = blockIdx.x & 7, slot = blockIdx.x >> 3;   // slot 0..71
    const int bm = xcd * 4 + slot / 18;
    const int rem = slot % 18, y = rem / 6, bn = rem % 6;
    const float* A    = (y == 0) ? q  : (y == 1) ? k  : v;
    const float* bias = (y == 0) ? bq : (y == 1) ? bk : bv;
    gemm_core_f32<0, 0>(A, Wbf + (long)y * 589824, bias, outp + (long)y * 3145728,
                        768, 768, bm, bn, As, Bs);
}

// ---------------------------------------------------------------------------
// 256x256-tile 8-wave 8-phase bf16 GEMM core, per-phase staging interleave
// (R10 version -- best measured). BK=64, 12 K-tiles, 2 LDS slots (dbuf).
// ---------------------------------------------------------------------------
template<int BIAS_MODE>
static __device__ __forceinline__ void gemm256_core(
    const short* __restrict__ A, const short* __restrict__ B,
    const float* __restrict__ bias, short* __restrict__ C,
    int lda, int ldc, int bm, int bn, short* As, short* Bs)
{
    const int tid = threadIdx.x, lane = tid & 63, w = tid >> 6;   // 8 waves
    const int wm = w & 1, wn = w >> 1;                            // 2 x 4
    const int qr = lane >> 4, lc = lane & 15, x7 = lc & 7;
    const int srow = tid >> 3, schunk = tid & 7;                  // srow 0..63
    const int gch = ((schunk ^ (srow & 7)) << 3);

    const short* Ab = A + (long)(bm * 256) * lda;
    const short* Bb = B + (long)(bn * 256) * 768;

    floatx4 acc[8][4];
#pragma unroll
    for (int i = 0; i < 8; i++)
#pragma unroll
        for (int j = 0; j < 4; j++) acc[i][j] = (floatx4){0.f, 0.f, 0.f, 0.f};

    // prologue: stage K-tile 0 -> slot 0 (8 gload_lds / thread, burst)
#pragma unroll
    for (int r = 0; r < 256; r += 64) {
        gload_lds16(Ab + (long)(r + srow) * lda + gch, As + (r + w * 8) * 64);
        gload_lds16(Bb + (long)(r + srow) * 768 + gch, Bs + (r + w * 8) * 64);
    }

#pragma unroll 1
    for (int kt = 0; kt < 12; ++kt) {
        const int s = kt & 1;
        const short* Ac = As + s * 16384;
        const short* Bc = Bs + s * 16384;
        short* Ad = As + (1 - s) * 16384;
        short* Bd = Bs + (1 - s) * 16384;
        const int koff = (kt + 1) * 64;

        // publish tile kt's staging (all waves), then fence slot reuse
        asm volatile("s_waitcnt vmcnt(0)" ::: "memory");
        __builtin_amdgcn_s_barrier();

        short8 af[4][2], bfr[2][2];
#pragma unroll
        for (int ph = 0; ph < 4; ++ph) {
            const int mh = ph >> 1, nh = ph & 1;
            // ds-load this phase's fragments (slot s)
            if (nh == 0) {   // A half-frags live for two phases
#pragma unroll
                for (int mi = 0; mi < 4; mi++)
#pragma unroll
                    for (int ks = 0; ks < 2; ks++)
                        af[mi][ks] = *(const short8*)&Ac[
                            (wm * 128 + (mh * 4 + mi) * 16 + lc) * 64 +
                            ((((ks << 2) + qr) ^ x7) << 3)];
            }
#pragma unroll
            for (int ni = 0; ni < 2; ni++)
#pragma unroll
                for (int ks = 0; ks < 2; ks++)
                    bfr[ni][ks] = *(const short8*)&Bc[
                        (wn * 64 + (nh * 2 + ni) * 16 + lc) * 64 +
                        ((((ks << 2) + qr) ^ x7) << 3)];
            // stage quarter ph of tile kt+1 -> slot 1-s (fine interleave)
            if (kt < 11) {
                const int r = ph * 64;
                gload_lds16(Ab + (long)(r + srow) * lda + koff + gch,
                            Ad + (r + w * 8) * 64);
                gload_lds16(Bb + (long)(r + srow) * 768 + koff + gch,
                            Bd + (r + w * 8) * 64);
            }
            __builtin_amdgcn_s_barrier();
            asm volatile("s_waitcnt lgkmcnt(0)" ::: "memory");
            __builtin_amdgcn_sched_barrier(0);
            __builtin_amdgcn_s_setprio(1);
#pragma unroll
            for (int ks = 0; ks < 2; ks++)
#pragma unroll
                for (int mi = 0; mi < 4; mi++)
#pragma unroll
                    for (int ni = 0; ni < 2; ni++)
                        acc[mh * 4 + mi][nh * 2 + ni] =
                            __builtin_amdgcn_mfma_f32_16x16x32_bf16(
                                af[mi][ks], bfr[ni][ks],
                                acc[mh * 4 + mi][nh * 2 + ni], 0, 0, 0);
            __builtin_amdgcn_s_setprio(0);
            __builtin_amdgcn_sched_barrier(0);
            __builtin_amdgcn_s_barrier();
        }
    }

    // epilogue
#pragma unroll
    for (int ni = 0; ni < 4; ni++) {
        const int gcol = bn * 256 + wn * 64 + ni * 16 + lc;
        const float bcol = (BIAS_MODE == 0) ? bias[gcol] : 0.f;
#pragma unroll
        for (int mi = 0; mi < 8; mi++) {
#pragma unroll
            for (int r = 0; r < 4; r++) {
                const int grow = bm * 256 + wm * 128 + mi * 16 + qr * 4 + r;
                const float bb = (BIAS_MODE == 1) ? bias[grow] : bcol;
                C[(long)grow * ldc + gcol] = f2bf(acc[mi][ni][r] + bb);
            }
        }
    }
}

// mid GEMMs fused: grid (432) x 512 thr, 128 KiB static LDS, 1 block/CU.
__global__ __launch_bounds__(512, 2) void mid_gemm2(
    const short* kproj, const short* vproj, const short* qproj, const short* Wbf,
    const float* bq_in, const float* bk_in, const float* bv_in,
    short* kiB, short* vtB, short* qiB)
{
    __shared__ short As[2 * 16384];   // 2 slots x 256 rows x 64 (64 KiB)
    __shared__ short Bs[2 * 16384];   // 64 KiB
    const int xcd = blockIdx.x & 7, slot = blockIdx.x >> 3;   // slot 0..53
    const int z = xcd, b = z >> 2, g = z & 3;
    if (slot < 24) {          // ki[s,f] = kproj @ Wk_in^T : M=2048, N=768
        gemm256_core<0>(kproj + (long)b * 1572864, Wbf + (long)(7 + g) * 589824,
                        bk_in + g * 768, kiB + (long)z * 1572864,
                        768, 768, slot / 3, slot % 3, As, Bs);
    } else if (slot < 48) {   // vt[f,s] = Wv_in @ vproj^T : M=768, N=2048
        const int s2 = slot - 24;
        gemm256_core<1>(Wbf + (long)(11 + g) * 589824, vproj + (long)b * 1572864,
                        bv_in + g * 768, vtB + (long)z * 1572864,
                        768, 2048, s2 / 8, s2 % 8, As, Bs);
    } else {                  // qi: M=512, interleaved gather (token = t*4+g)
        const int s3 = slot - 48;
        gemm256_core<0>(qproj + (long)b * 1572864 + g * 768, Wbf + (long)(3 + g) * 589824,
                        bq_in + g * 768, qiB + (long)z * 393216,
                        3072, 768, s3 / 3, s3 % 3, As, Bs);
    }
}

// ---------------------------------------------------------------------------
// out projection with deferred softmax-normalization:
// A_eff[row][e] = (P0+P1)[row][e] / (L0+L1)[row][e>>6], cvt bf16 in staging.
// C = A_eff @ Wout^T + bout, fp32 C scattered (ldc=3072). grid (192).
// ---------------------------------------------------------------------------
static __device__ __forceinline__ void gemm_core_out(
    const float* __restrict__ P0, const float* __restrict__ P1,
    const float* __restrict__ L0, const float* __restrict__ L1,
    const short* __restrict__ Wb, const float* __restrict__ bp,
    float* __restrict__ Cv, int z, int bm, int bn, short* As, short* Bs)
{
    GEMM_LANE_VARS
    const short* Wt = Wb + (long)(bn * 128) * 768;

    floatx4 acc[4][4];
#pragma unroll
    for (int mi = 0; mi < 4; mi++)
#pragma unroll
        for (int ni = 0; ni < 4; ni++) acc[mi][ni] = (floatx4){0.f, 0.f, 0.f, 0.f};

    for (int k0 = 0; k0 < 768; k0 += 64) {
        __syncthreads();
        const int e = k0 + schunk * 8, he = e >> 6;
#pragma unroll
        for (int p = 0; p < 4; p++) {
            const int row = p * 32 + srow;
            const long gz = (long)z * 512 + bm * 128 + row;
            const float* a0 = P0 + gz * 768 + e;
            const float* a1 = P1 + gz * 768 + e;
            floatx4 f0 = *(const floatx4*)a0;
            floatx4 f1 = *(const floatx4*)(a0 + 4);
            floatx4 g0 = *(const floatx4*)a1;
            floatx4 g1 = *(const floatx4*)(a1 + 4);
            const float linv = 1.f / (L0[gz * 12 + he] + L1[gz * 12 + he]);
            f0 = (f0 + g0) * linv;
            f1 = (f1 + g1) * linv;
            *(short8*)&As[row * 64 + ((schunk ^ sx) << 3)] = f8_to_bf8(f0, f1);
            gload_lds16(Wt + (long)row * 768 + k0 + ((schunk ^ sx) << 3),
                        &Bs[(p * 32 + w * 8) * 64]);
        }
        __syncthreads();
        gemm_mfma_step(acc, As, Bs, wm, wn, qr, lc, x7);
    }
    gemm_epilogue<2, 0>(acc, bp, Cv, 3072, bm, bn, wm, wn, qr, lc);
}

__global__ __launch_bounds__(256) void out_gemm(
    const float* P0, const float* P1, const float* L0, const float* L1,
    const short* Wbf, const float* bout, float* out)
{
    extern __shared__ short sm[];
    short* As = sm;
    short* Bs = sm + 16384;
    const int xcd = blockIdx.x & 7, slot = blockIdx.x >> 3;   // slot 0..23
    const int z = xcd, b = z >> 2, g = z & 3;
    gemm_core_out(P0, P1, L0, L1, Wbf + (long)(15 + g) * 589824,
                  bout + g * 768, out + (long)b * 1572864 + g * 768,
                  z, slot / 6, slot % 6, As, Bs);
}

// ---------------------------------------------------------------------------
// Flash attention, k-split, lane-local softmax, 2 q-subtiles/wave.
// Block = 4 waves x 32 q-rows = 128 q-rows, k-range = khalf*1024..+1023
// (16 KV tiles). grid = 96 heads x 4 qtiles x 2 khalves = 768 -> 12 w/CU.
// QK^T swapped (A=K, B=Q); K rows staged PERMUTED (kperm) so each lane's
// 16 produced k's are its PV A-frag k's; P in registers via cvt_pk.
// No-max softmax => k-partials additive: writes UNNORMALIZED f32 cacc to
// P[kh] and row-sums to L[kh]; out_gemm combines+normalizes.
// ---------------------------------------------------------------------------
__global__ __launch_bounds__(256) void attn_kernel(
    const short* __restrict__ qi, const short* __restrict__ ki,
    const short* __restrict__ vt,
    float* __restrict__ P0, float* __restrict__ P1,
    float* __restrict__ L0, float* __restrict__ L1)
{
    __shared__ short Kt[2][64 * 64];
    __shared__ short Vt[2][64 * 64];

    const int tid = threadIdx.x, lane = tid & 63, w = tid >> 6;   // 4 waves
    const int qr = lane >> 4, lc = lane & 15, x7 = lc & 7;
    const int headid = blockIdx.x % 96;
    const int qk = blockIdx.x / 96;                // 0..7
    const int qt = qk >> 1, kh = qk & 1;
    const int h = headid % 12, bg = headid / 12;
    const long qrow0 = (long)bg * 512 + qt * 128 + w * 32;   // wave's 32 rows
    const int kbase = kh * 16;                     // tile units of 64

    short8 aq[2][2];
#pragma unroll
    for (int t = 0; t < 2; t++) {
        const short* qp = qi + (qrow0 + t * 16 + lc) * 768 + h * 64 + qr * 8;
        aq[t][0] = *(const short8*)qp;
        aq[t][1] = *(const short8*)(qp + 32);
    }

    floatx4 cacc[2][4];
    float lsum[2] = {0.f, 0.f};
#pragma unroll
    for (int t = 0; t < 2; t++)
#pragma unroll
        for (int dc = 0; dc < 4; dc++) cacc[t][dc] = (floatx4){0.f, 0.f, 0.f, 0.f};

    const int srow = lane >> 3, schk = lane & 7, swz = schk ^ srow;
    const short* kgb = ki + ((long)bg * 2048) * 768 + h * 64;
    const short* vgb = vt + ((long)(bg * 768 + h * 64)) * 2048;

    // K-row permutation (loop-invariant): dest rows d0/d1 for inst 0/1
#define KPERM(d) ((((d) >> 5) & 1) * 32 + (((d) >> 2) & 3) * 8 + (((d) >> 4) & 1) * 4 + ((d) & 3))
    const int d0 = w * 16 + srow, d1 = d0 + 8;
    const int kp0 = KPERM(d0), kp1 = KPERM(d1);
#undef KPERM

    {   // prologue staging: tile kbase (K permuted, V linear)
        const int s0 = kbase * 64;
        gload_lds16(kgb + (long)(s0 + kp0) * 768 + swz * 8, &Kt[0][(w * 16) * 64]);
        gload_lds16(kgb + (long)(s0 + kp1) * 768 + swz * 8, &Kt[0][(w * 16 + 8) * 64]);
        gload_lds16(vgb + (long)d0 * 2048 + s0 + swz * 8, &Vt[0][(w * 16) * 64]);
        gload_lds16(vgb + (long)d1 * 2048 + s0 + swz * 8, &Vt[0][(w * 16 + 8) * 64]);
    }

    for (int j = 0; j < 16; j++) {
        const int cur = j & 1;
        __syncthreads();
        if (j < 15) {
            const int nxt = cur ^ 1, s0 = (kbase + j + 1) * 64;
            gload_lds16(kgb + (long)(s0 + kp0) * 768 + swz * 8, &Kt[nxt][(w * 16) * 64]);
            gload_lds16(kgb + (long)(s0 + kp1) * 768 + swz * 8, &Kt[nxt][(w * 16 + 8) * 64]);
            gload_lds16(vgb + (long)d0 * 2048 + s0 + swz * 8, &Vt[nxt][(w * 16) * 64]);
            gload_lds16(vgb + (long)d1 * 2048 + s0 + swz * 8, &Vt[nxt][(w * 16 + 8) * 64]);
        }

        const short* Kb = &Kt[cur][0];
        const short* Vb = &Vt[cur][0];

        // QK^T swapped: sv[t][ss][r] = S[k = 32*(ss>>1)+8*qr+4*(ss&1)+r][q]
        floatx4 sv[2][4];
        __builtin_amdgcn_s_setprio(1);
#pragma unroll
        for (int ss = 0; ss < 4; ss++) {
            const short* kr = Kb + (ss * 16 + lc) * 64;
            short8 b0 = *(const short8*)(kr + ((qr ^ x7) << 3));
            short8 b1 = *(const short8*)(kr + (((4 + qr) ^ x7) << 3));
#pragma unroll
            for (int t = 0; t < 2; t++) {
                floatx4 acc0 = (floatx4){0.f, 0.f, 0.f, 0.f};
                acc0 = __builtin_amdgcn_mfma_f32_16x16x32_bf16(b0, aq[t][0], acc0, 0, 0, 0);
                acc0 = __builtin_amdgcn_mfma_f32_16x16x32_bf16(b1, aq[t][1], acc0, 0, 0, 0);
                sv[t][ss] = acc0;
            }
        }
        __builtin_amdgcn_s_setprio(0);

        // lane-local softmax per sub-tile: exp2, sum, pack to bf16 pairs
        short8 ap[2][2];
#pragma unroll
        for (int t = 0; t < 2; t++) {
            float p[4][4];
#pragma unroll
            for (int ss = 0; ss < 4; ss++)
#pragma unroll
                for (int r = 0; r < 4; r++)
                    p[ss][r] = __builtin_amdgcn_exp2f(sv[t][ss][r] * 0.18033688f);
#pragma unroll
            for (int ss = 0; ss < 4; ss++)
                lsum[t] += (p[ss][0] + p[ss][1]) + (p[ss][2] + p[ss][3]);
            intx4 i0, i1;
            i0[0] = (int)cvt_pk_bf16(p[0][0], p[0][1]);
            i0[1] = (int)cvt_pk_bf16(p[0][2], p[0][3]);
            i0[2] = (int)cvt_pk_bf16(p[1][0], p[1][1]);
            i0[3] = (int)cvt_pk_bf16(p[1][2], p[1][3]);
            i1[0] = (int)cvt_pk_bf16(p[2][0], p[2][1]);
            i1[1] = (int)cvt_pk_bf16(p[2][2], p[2][3]);
            i1[2] = (int)cvt_pk_bf16(p[3][0], p[3][1]);
            i1[3] = (int)cvt_pk_bf16(p[3][2], p[3][3]);
            ap[t][0] = __builtin_bit_cast(short8, i0);   // k = 8qr..8qr+7
            ap[t][1] = __builtin_bit_cast(short8, i1);   // k = 32+8qr..+7
        }

        __builtin_amdgcn_s_setprio(1);
#pragma unroll
        for (int dc = 0; dc < 4; dc++) {
            const short* vr = Vb + (dc * 16 + lc) * 64;
            short8 bv0 = *(const short8*)(vr + ((qr ^ x7) << 3));
            short8 bv1 = *(const short8*)(vr + (((4 + qr) ^ x7) << 3));
#pragma unroll
            for (int t = 0; t < 2; t++) {
                cacc[t][dc] = __builtin_amdgcn_mfma_f32_16x16x32_bf16(
                    ap[t][0], bv0, cacc[t][dc], 0, 0, 0);
                cacc[t][dc] = __builtin_amdgcn_mfma_f32_16x16x32_bf16(
                    ap[t][1], bv1, cacc[t][dc], 0, 0, 0);
            }
        }
        __builtin_amdgcn_s_setprio(0);
    }

    // l reduce; after the xors every lane holds the total for q = lc
#pragma unroll
    for (int t = 0; t < 2; t++) {
        lsum[t] += __shfl_xor(lsum[t], 16);
        lsum[t] += __shfl_xor(lsum[t], 32);
    }

    // UNNORMALIZED partial writes (f32)
    float* Pk = kh ? P1 : P0;
    float* Lk = kh ? L1 : L0;
    float* cp = Pk + qrow0 * 768 + h * 64;
#pragma unroll
    for (int t = 0; t < 2; t++) {
#pragma unroll
        for (int dc = 0; dc < 4; dc++)
#pragma unroll
            for (int r = 0; r < 4; r++)
                cp[(t * 16 + qr * 4 + r) * 768 + dc * 16 + lc] = cacc[t][dc][r];
        if (qr == 0)
            Lk[(qrow0 + t * 16 + lc) * 12 + h] = lsum[t];
    }
}

// ---------------------------------------------------------------------------
extern "C" void kernel_launch(void* const* d_in, const int* in_sizes, int n_in,
                              void* d_out, int out_size, void* d_ws, size_t ws_size,
                              hipStream_t stream) {
    const float* query = (const float*)d_in[0];
    const float* key   = (const float*)d_in[1];
    const float* value = (const float*)d_in[2];
    const float* Wqg = (const float*)d_in[3];  const float* bqg = (const float*)d_in[4];
    const float* Wk  = (const float*)d_in[5];  const float* bk  = (const float*)d_in[6];
    const float* Wv  = (const float*)d_in[7];  const float* bv  = (const float*)d_in[8];
    const float* Wq_in = (const float*)d_in[9];  const float* bq_in = (const float*)d_in[10];
    const float* Wk_in = (const float*)d_in[11]; const float* bk_in = (const float*)d_in[12];
    const float* Wv_in = (const float*)d_in[13]; const float* bv_in = (const float*)d_in[14];
    const float* Wout  = (const float*)d_in[15]; const float* bout  = (const float*)d_in[16];
    float* out = (float*)d_out;

    // workspace (shorts), ~98 MB:
    short* ws     = (short*)d_ws;
    short* Wbf    = ws;                  // [0, 11206656)
    short* q_proj = ws + 11206656L;      // q | k | v, 3 x 3145728
    short* k_proj = ws + 14352384L;
    short* v_proj = ws + 17498112L;
    short* qiB    = ws + 20643840L;      // 3145728
    short* vtB    = ws + 23789568L;      // 12582912
    short* kiB    = ws + 36372480L;      // 12582912, end 48955392
    // dead-after-mid aliases (attn/out phase):
    float* P0 = (float*)ws;                       // 3145728 f32 = Wbf[0..6291456) shorts (W 0..10, dead; Wout@15U safe)
    float* P1 = (float*)(ws + 11206656L);         // q_proj+k_proj region, exactly 6291456 shorts
    float* L0 = (float*)(ws + 17498112L);         // v_proj region: 49152 f32
    float* L1 = (float*)(ws + 17596416L);         // 49152 f32, ends 17694720 < qiB

    dim3 blk(256);

    cast_w<<<dim3(5472), blk, 0, stream>>>(
        Wqg, Wk, Wv, Wq_in, Wk_in, Wv_in, Wout, Wbf);

    qkv_gemm<<<dim3(576), blk, 0, stream>>>(
        query, key, value, Wbf, bqg, bk, bv, q_proj);

    mid_gemm2<<<dim3(432), dim3(512), 0, stream>>>(
        k_proj, v_proj, q_proj, Wbf, bq_in, bk_in, bv_in, kiB, vtB, qiB);

    attn_kernel<<<dim3(768), blk, 0, stream>>>(qiB, kiB, vtB, P0, P1, L0, L1);

    out_gemm<<<dim3(192), blk, 65536, stream>>>(P0, P1, L0, L1, Wbf, bout, out);
}

// Round 9
// 292.781 us; speedup vs baseline: 1.0647x; 1.0647x over previous
//
#include <hip/hip_runtime.h>
#include <hip/hip_bf16.h>

// GroupQueryAttention: B=2,S=2048,E=768,H=12,G=4,D=64,T=512
// R17 = R13 (banked best, 289.8us: attn lane-local softmax + bf16 ctxB,
//      out_gemm = gemm_core_db on ctxB) with ONE change: qkv_gemm's core
//      upgraded from single-buffered 2-barrier (sync-stage-sync-compute)
//      to the in-file proven double-buffered 1-barrier schedule
//      (gemm_core_f32db): issue tile kk+1's 8 f32 A-loads + 4 B gload_lds
//      after the top barrier, compute tile kk (hides HBM latency), then
//      cvt+ds_write the A prefetch into slot kk+1 (race-free: that slot's
//      reads retired before this iteration's barrier). LDS 32->64KB
//      (2 blocks/CU at grid 576). R16's k-split attn REVERTED (-21.9us:
//      f32 partial traffic cost more than 12w/CU amortization gained).

typedef __attribute__((ext_vector_type(8))) short short8;
typedef __attribute__((ext_vector_type(4))) float floatx4;
typedef __attribute__((ext_vector_type(4))) int intx4;

static __device__ __forceinline__ short f2bf(float f) {
    __bf16 b = (__bf16)f;              // fptrunc RNE -> HW cvt
    return __builtin_bit_cast(short, b);
}
static __device__ __forceinline__ short8 f8_to_bf8(floatx4 f0, floatx4 f1) {
    short8 s;
    s[0]=f2bf(f0[0]); s[1]=f2bf(f0[1]); s[2]=f2bf(f0[2]); s[3]=f2bf(f0[3]);
    s[4]=f2bf(f1[0]); s[5]=f2bf(f1[1]); s[6]=f2bf(f1[2]); s[7]=f2bf(f1[3]);
    return s;
}
static __device__ __forceinline__ unsigned cvt_pk_bf16(float a, float b) {
    unsigned r;                        // D[15:0]=bf16(a), D[31:16]=bf16(b)
    asm("v_cvt_pk_bf16_f32 %0, %1, %2" : "=v"(r) : "v"(a), "v"(b));
    return r;
}
static __device__ __forceinline__ void gload_lds16(const short* g, short* l) {
    __builtin_amdgcn_global_load_lds(
        (const __attribute__((address_space(1))) unsigned int*)g,
        (__attribute__((address_space(3))) unsigned int*)l, 16, 0, 0);
}

// ---------------------------------------------------------------------------
// weights fp32->bf16 (7 tensors, 19*768^2 elems contiguous dst)
// ---------------------------------------------------------------------------
__global__ __launch_bounds__(256) void cast_w(
    const float* a0, const float* a1, const float* a2, const float* a3,
    const float* a4, const float* a5, const float* a6, short* dst)
{
    const long U = 589824L;
    const float* ptrs[7] = {a0,a1,a2,a3,a4,a5,a6};
    const long starts[8] = {0, U, 2*U, 3*U, 7*U, 11*U, 15*U, 19*U};
    long i = (long)blockIdx.x * 2048 + (long)threadIdx.x * 8;
    int t = 0;
    while (t < 6 && i >= starts[t + 1]) t++;
    const float* s = ptrs[t] + (i - starts[t]);
    floatx4 f0 = *(const floatx4*)s;
    floatx4 f1 = *(const floatx4*)(s + 4);
    *(short8*)(dst + i) = f8_to_bf8(f0, f1);
}

// ---------------------------------------------------------------------------
// 128x128 MFMA core pieces. C/D layout: col=lane&15, row=quad*4+reg.
// ---------------------------------------------------------------------------
#define GEMM_LANE_VARS                                                        \
    const int tid = threadIdx.x, lane = tid & 63, w = tid >> 6;               \
    const int wm = w & 1, wn = w >> 1;                                        \
    const int qr = lane >> 4, lc = lane & 15, x7 = lc & 7;                    \
    const int srow = tid >> 3, schunk = tid & 7, sx = srow & 7;

template<int CMODE, int BIAS_MODE>
static __device__ __forceinline__ void gemm_epilogue(
    floatx4 (&acc)[4][4], const float* bp, void* Cv, int ldc, int bm, int bn,
    int wm, int wn, int qr, int lc)
{
#pragma unroll
    for (int ni = 0; ni < 4; ni++) {
        const int gcol = bn * 128 + wn * 64 + ni * 16 + lc;
        const float bcol = (BIAS_MODE == 0) ? bp[gcol] : 0.f;
#pragma unroll
        for (int mi = 0; mi < 4; mi++) {
#pragma unroll
            for (int r = 0; r < 4; r++) {
                const int grow = bm * 128 + wm * 64 + mi * 16 + qr * 4 + r;
                const float bb = (BIAS_MODE == 1) ? bp[grow] : bcol;
                const float v = acc[mi][ni][r] + bb;
                if (CMODE == 0)
                    ((short*)Cv)[(long)grow * ldc + gcol] = f2bf(v);
                else
                    ((float*)Cv)[(long)grow * ldc + gcol] = v;
            }
        }
    }
}

static __device__ __forceinline__ void gemm_mfma_step(
    floatx4 (&acc)[4][4], const short* Ac, const short* Bc,
    int wm, int wn, int qr, int lc, int x7)
{
#pragma unroll
    for (int ks = 0; ks < 64; ks += 32) {
        const int c0 = (ks >> 3) + qr;
        const int slot = ((c0 ^ x7) << 3);
        short8 af[4], bfr[4];
#pragma unroll
        for (int mi = 0; mi < 4; mi++)
            af[mi] = *(const short8*)&Ac[(wm * 64 + mi * 16 + lc) * 64 + slot];
#pragma unroll
        for (int ni = 0; ni < 4; ni++)
            bfr[ni] = *(const short8*)&Bc[(wn * 64 + ni * 16 + lc) * 64 + slot];
#pragma unroll
        for (int mi = 0; mi < 4; mi++)
#pragma unroll
            for (int ni = 0; ni < 4; ni++)
                acc[mi][ni] = __builtin_amdgcn_mfma_f32_16x16x32_bf16(
                    af[mi], bfr[ni], acc[mi][ni], 0, 0, 0);
    }
}

// ---------------------------------------------------------------------------
// Double-buffered 128x128 bf16 core (used by out_gemm).
// ---------------------------------------------------------------------------
template<int CMODE, int BIAS_MODE>
static __device__ __forceinline__ void gemm_core_db(
    const short* __restrict__ A, const short* __restrict__ Wb,
    const float* __restrict__ bp, void* __restrict__ Cv,
    int lda, int ldc, int bm, int bn, short* As, short* Bs)
{
    GEMM_LANE_VARS
    const short* Ab = A + (long)(bm * 128) * lda;
    const short* Wt = Wb + (long)(bn * 128) * 768;
    const int gch = ((schunk ^ sx) << 3);

    floatx4 acc[4][4];
#pragma unroll
    for (int mi = 0; mi < 4; mi++)
#pragma unroll
        for (int ni = 0; ni < 4; ni++) acc[mi][ni] = (floatx4){0.f, 0.f, 0.f, 0.f};

#pragma unroll
    for (int p = 0; p < 4; p++) {
        gload_lds16(Ab + (long)(p * 32 + srow) * lda + gch, &As[(p * 32 + w * 8) * 64]);
        gload_lds16(Wt + (long)(p * 32 + srow) * 768 + gch, &Bs[(p * 32 + w * 8) * 64]);
    }

    for (int kk = 0; kk < 12; kk++) {
        __syncthreads();   // drains loads for tile kk (issued last iter); fences buf reuse
        if (kk < 11) {
            const int k1 = (kk + 1) * 64;
            const int nb = ((kk + 1) & 1) * 8192;
#pragma unroll
            for (int p = 0; p < 4; p++) {
                gload_lds16(Ab + (long)(p * 32 + srow) * lda + k1 + gch,
                            &As[nb + (p * 32 + w * 8) * 64]);
                gload_lds16(Wt + (long)(p * 32 + srow) * 768 + k1 + gch,
                            &Bs[nb + (p * 32 + w * 8) * 64]);
            }
        }
        gemm_mfma_step(acc, As + (kk & 1) * 8192, Bs + (kk & 1) * 8192,
                       wm, wn, qr, lc, x7);
    }
    gemm_epilogue<CMODE, BIAS_MODE>(acc, bp, Cv, ldc, bm, bn, wm, wn, qr, lc);
}

// ---------------------------------------------------------------------------
// Double-buffered core for fp32 A (qkv). 1 barrier/iter: after the top
// barrier publishes tile kk, issue tile kk+1's 8 f32 A-loads + 4 B
// gload_lds (-> slot 1-s), compute tile kk (hides HBM latency), then
// cvt+ds_write the A prefetch into slot 1-s. Race-free: slot 1-s's reads
// (tile kk-1) all retired before this iteration's top barrier.
// ---------------------------------------------------------------------------
template<int CMODE, int BIAS_MODE>
static __device__ __forceinline__ void gemm_core_f32db(
    const float* __restrict__ A, const short* __restrict__ Wb,
    const float* __restrict__ bp, void* __restrict__ Cv,
    int lda, int ldc, int bm, int bn, short* As, short* Bs)
{
    GEMM_LANE_VARS
    const short* Wt = Wb + (long)(bn * 128) * 768;
    const int gch = ((schunk ^ sx) << 3);

    floatx4 acc[4][4];
#pragma unroll
    for (int mi = 0; mi < 4; mi++)
#pragma unroll
        for (int ni = 0; ni < 4; ni++) acc[mi][ni] = (floatx4){0.f, 0.f, 0.f, 0.f};

    floatx4 a0[4], a1[4];
    // prologue: tile 0 -> slot 0
#pragma unroll
    for (int p = 0; p < 4; p++) {
        const float* ap = A + (long)(bm * 128 + p * 32 + srow) * lda + schunk * 8;
        a0[p] = *(const floatx4*)ap;
        a1[p] = *(const floatx4*)(ap + 4);
        gload_lds16(Wt + (long)(p * 32 + srow) * 768 + gch, &Bs[(p * 32 + w * 8) * 64]);
    }
#pragma unroll
    for (int p = 0; p < 4; p++)
        *(short8*)&As[(p * 32 + srow) * 64 + gch] = f8_to_bf8(a0[p], a1[p]);

    for (int kk = 0; kk < 12; kk++) {
        __syncthreads();   // publishes tile kk (B gloads + A ds_writes); fences slot reuse
        const int s = (kk & 1) * 8192;
        if (kk < 11) {
            const int k1 = (kk + 1) * 64;
            const int nb = ((kk + 1) & 1) * 8192;
#pragma unroll
            for (int p = 0; p < 4; p++) {
                const float* ap = A + (long)(bm * 128 + p * 32 + srow) * lda + k1 + schunk * 8;
                a0[p] = *(const floatx4*)ap;
                a1[p] = *(const floatx4*)(ap + 4);
                gload_lds16(Wt + (long)(p * 32 + srow) * 768 + k1 + gch,
                            &Bs[nb + (p * 32 + w * 8) * 64]);
            }
            gemm_mfma_step(acc, As + s, Bs + s, wm, wn, qr, lc, x7);
#pragma unroll
            for (int p = 0; p < 4; p++)
                *(short8*)&As[nb + (p * 32 + srow) * 64 + gch] = f8_to_bf8(a0[p], a1[p]);
        } else {
            gemm_mfma_step(acc, As + s, Bs + s, wm, wn, qr, lc, x7);
        }
    }
    gemm_epilogue<CMODE, BIAS_MODE>(acc, bp, Cv, ldc, bm, bn, wm, wn, qr, lc);
}

// qkv projections: grid (576). XCD k owns bm in [4k,4k+4); order bm->y->bn.
__global__ __launch_bounds__(256) void qkv_gemm(
    const float* q, const float* k, const float* v, const short* Wbf,
    const float* bq, const float* bk, const float* bv, short* outp)
{
    __shared__ short As[2 * 8192];   // 2 slots x 128 x 64 (32 KiB)
    __shared__ short Bs[2 * 8192];   // 32 KiB
    const int xcd = blockIdx.x & 7, slot = blockIdx.x >> 3;   // slot 0..71
    const int bm = xcd * 4 + slot / 18;
    const int rem = slot % 18, y = rem / 6, bn = rem % 6;
    const float* A    = (y == 0) ? q  : (y == 1) ? k  : v;
    const float* bias = (y == 0) ? bq : (y == 1) ? bk : bv;
    gemm_core_f32db<0, 0>(A, Wbf + (long)y * 589824, bias, outp + (long)y * 3145728,
                          768, 768, bm, bn, As, Bs);
}

// ---------------------------------------------------------------------------
// 256x256-tile 8-wave 8-phase bf16 GEMM core, per-phase staging interleave
// (R10 version -- best measured). BK=64, 12 K-tiles, 2 LDS slots (dbuf).
// ---------------------------------------------------------------------------
template<int BIAS_MODE>
static __device__ __forceinline__ void gemm256_core(
    const short* __restrict__ A, const short* __restrict__ B,
    const float* __restrict__ bias, short* __restrict__ C,
    int lda, int ldc, int bm, int bn, short* As, short* Bs)
{
    const int tid = threadIdx.x, lane = tid & 63, w = tid >> 6;   // 8 waves
    const int wm = w & 1, wn = w >> 1;                            // 2 x 4
    const int qr = lane >> 4, lc = lane & 15, x7 = lc & 7;
    const int srow = tid >> 3, schunk = tid & 7;                  // srow 0..63
    const int gch = ((schunk ^ (srow & 7)) << 3);

    const short* Ab = A + (long)(bm * 256) * lda;
    const short* Bb = B + (long)(bn * 256) * 768;

    floatx4 acc[8][4];
#pragma unroll
    for (int i = 0; i < 8; i++)
#pragma unroll
        for (int j = 0; j < 4; j++) acc[i][j] = (floatx4){0.f, 0.f, 0.f, 0.f};

    // prologue: stage K-tile 0 -> slot 0 (8 gload_lds / thread, burst)
#pragma unroll
    for (int r = 0; r < 256; r += 64) {
        gload_lds16(Ab + (long)(r + srow) * lda + gch, As + (r + w * 8) * 64);
        gload_lds16(Bb + (long)(r + srow) * 768 + gch, Bs + (r + w * 8) * 64);
    }

#pragma unroll 1
    for (int kt = 0; kt < 12; ++kt) {
        const int s = kt & 1;
        const short* Ac = As + s * 16384;
        const short* Bc = Bs + s * 16384;
        short* Ad = As + (1 - s) * 16384;
        short* Bd = Bs + (1 - s) * 16384;
        const int koff = (kt + 1) * 64;

        // publish tile kt's staging (all waves), then fence slot reuse
        asm volatile("s_waitcnt vmcnt(0)" ::: "memory");
        __builtin_amdgcn_s_barrier();

        short8 af[4][2], bfr[2][2];
#pragma unroll
        for (int ph = 0; ph < 4; ++ph) {
            const int mh = ph >> 1, nh = ph & 1;
            // ds-load this phase's fragments (slot s)
            if (nh == 0) {   // A half-frags live for two phases
#pragma unroll
                for (int mi = 0; mi < 4; mi++)
#pragma unroll
                    for (int ks = 0; ks < 2; ks++)
                        af[mi][ks] = *(const short8*)&Ac[
                            (wm * 128 + (mh * 4 + mi) * 16 + lc) * 64 +
                            ((((ks << 2) + qr) ^ x7) << 3)];
            }
#pragma unroll
            for (int ni = 0; ni < 2; ni++)
#pragma unroll
                for (int ks = 0; ks < 2; ks++)
                    bfr[ni][ks] = *(const short8*)&Bc[
                        (wn * 64 + (nh * 2 + ni) * 16 + lc) * 64 +
                        ((((ks << 2) + qr) ^ x7) << 3)];
            // stage quarter ph of tile kt+1 -> slot 1-s (fine interleave)
            if (kt < 11) {
                const int r = ph * 64;
                gload_lds16(Ab + (long)(r + srow) * lda + koff + gch,
                            Ad + (r + w * 8) * 64);
                gload_lds16(Bb + (long)(r + srow) * 768 + koff + gch,
                            Bd + (r + w * 8) * 64);
            }
            __builtin_amdgcn_s_barrier();
            asm volatile("s_waitcnt lgkmcnt(0)" ::: "memory");
            __builtin_amdgcn_sched_barrier(0);
            __builtin_amdgcn_s_setprio(1);
#pragma unroll
            for (int ks = 0; ks < 2; ks++)
#pragma unroll
                for (int mi = 0; mi < 4; mi++)
#pragma unroll
                    for (int ni = 0; ni < 2; ni++)
                        acc[mh * 4 + mi][nh * 2 + ni] =
                            __builtin_amdgcn_mfma_f32_16x16x32_bf16(
                                af[mi][ks], bfr[ni][ks],
                                acc[mh * 4 + mi][nh * 2 + ni], 0, 0, 0);
            __builtin_amdgcn_s_setprio(0);
            __builtin_amdgcn_sched_barrier(0);
            __builtin_amdgcn_s_barrier();
        }
    }

    // epilogue
#pragma unroll
    for (int ni = 0; ni < 4; ni++) {
        const int gcol = bn * 256 + wn * 64 + ni * 16 + lc;
        const float bcol = (BIAS_MODE == 0) ? bias[gcol] : 0.f;
#pragma unroll
        for (int mi = 0; mi < 8; mi++) {
#pragma unroll
            for (int r = 0; r < 4; r++) {
                const int grow = bm * 256 + wm * 128 + mi * 16 + qr * 4 + r;
                const float bb = (BIAS_MODE == 1) ? bias[grow] : bcol;
                C[(long)grow * ldc + gcol] = f2bf(acc[mi][ni][r] + bb);
            }
        }
    }
}

// mid GEMMs fused: grid (432) x 512 thr, 128 KiB static LDS, 1 block/CU.
// XCD k owns z=(b,g)=k. slots per z: 24 ki + 24 vt + 6 qi.
__global__ __launch_bounds__(512, 2) void mid_gemm2(
    const short* kproj, const short* vproj, const short* qproj, const short* Wbf,
    const float* bq_in, const float* bk_in, const float* bv_in,
    short* kiB, short* vtB, short* qiB)
{
    __shared__ short As[2 * 16384];   // 2 slots x 256 rows x 64 (64 KiB)
    __shared__ short Bs[2 * 16384];   // 64 KiB
    const int xcd = blockIdx.x & 7, slot = blockIdx.x >> 3;   // slot 0..53
    const int z = xcd, b = z >> 2, g = z & 3;
    if (slot < 24) {          // ki[s,f] = kproj @ Wk_in^T : M=2048, N=768
        gemm256_core<0>(kproj + (long)b * 1572864, Wbf + (long)(7 + g) * 589824,
                        bk_in + g * 768, kiB + (long)z * 1572864,
                        768, 768, slot / 3, slot % 3, As, Bs);
    } else if (slot < 48) {   // vt[f,s] = Wv_in @ vproj^T : M=768, N=2048
        const int s2 = slot - 24;
        gemm256_core<1>(Wbf + (long)(11 + g) * 589824, vproj + (long)b * 1572864,
                        bv_in + g * 768, vtB + (long)z * 1572864,
                        768, 2048, s2 / 8, s2 % 8, As, Bs);
    } else {                  // qi: M=512, interleaved gather (token = t*4+g)
        const int s3 = slot - 48;
        gemm256_core<0>(qproj + (long)b * 1572864 + g * 768, Wbf + (long)(3 + g) * 589824,
                        bq_in + g * 768, qiB + (long)z * 393216,
                        3072, 768, s3 / 3, s3 % 3, As, Bs);
    }
}

// out projection: grid (192), dyn LDS 64 KB. fp32 C scattered (ldc=3072).
__global__ __launch_bounds__(256) void out_gemm(
    const short* ctxB, const short* Wbf, const float* bout, float* out)
{
    extern __shared__ short sm[];
    short* As = sm;
    short* Bs = sm + 16384;
    const int xcd = blockIdx.x & 7, slot = blockIdx.x >> 3;   // slot 0..23
    const int z = xcd, b = z >> 2, g = z & 3;
    gemm_core_db<2, 0>(ctxB + (long)z * 393216, Wbf + (long)(15 + g) * 589824,
                       bout + g * 768, out + (long)b * 1572864 + g * 768,
                       768, 3072, slot / 6, slot % 6, As, Bs);
}

// ---------------------------------------------------------------------------
// Flash attention, lane-local softmax (R13 -- banked best). 1 WG = 64 q-rows
// of one (b,g,h). QK^T swapped (A=K, B=Q): lane (qr,lc) owns P[k][q=lc].
// K rows staged PERMUTED so lane-owned k's == PV A-frag k's:
//   dest row d holds global row kperm(d) = 32*d5 + 8*((d>>2)&3) + 4*d4 + (d&3)
//   => tile ss, reg r: k = 32*(ss>>1) + 8*qr + 4*(ss&1) + r
// P never touches LDS; l-sum = per-lane f32, reduced once at the end.
// ---------------------------------------------------------------------------
__global__ __launch_bounds__(256) void attn_kernel(
    const short* __restrict__ qi, const short* __restrict__ ki,
    const short* __restrict__ vt, short* __restrict__ ctx)
{
    __shared__ short Kt[2][64 * 64];
    __shared__ short Vt[2][64 * 64];

    const int tid = threadIdx.x, lane = tid & 63, w = tid >> 6;
    const int qr = lane >> 4, lc = lane & 15, x7 = lc & 7;
    const int headid = blockIdx.x % 96;
    const int tile = blockIdx.x / 96;
    const int h = headid % 12, bg = headid / 12;

    const short* qp = qi + ((long)bg * 512 + tile * 64 + w * 16 + lc) * 768 + h * 64 + qr * 8;
    const short8 aq0 = *(const short8*)qp;
    const short8 aq1 = *(const short8*)(qp + 32);

    floatx4 cacc[4];
    float lsum = 0.f;
#pragma unroll
    for (int dc = 0; dc < 4; dc++) cacc[dc] = (floatx4){0.f, 0.f, 0.f, 0.f};

    const int srow = lane >> 3, schk = lane & 7, swz = schk ^ srow;
    const short* kgb = ki + ((long)bg * 2048) * 768 + h * 64;
    const short* vgb = vt + ((long)(bg * 768 + h * 64)) * 2048;

    // K-row permutation (loop-invariant): dest rows d0/d1 for inst 0/1
#define KPERM(d) ((((d) >> 5) & 1) * 32 + (((d) >> 2) & 3) * 8 + (((d) >> 4) & 1) * 4 + ((d) & 3))
    const int d0 = w * 16 + srow, d1 = d0 + 8;
    const int kp0 = KPERM(d0), kp1 = KPERM(d1);
#undef KPERM

    {   // prologue staging (K permuted, V linear)
        gload_lds16(kgb + (long)kp0 * 768 + swz * 8, &Kt[0][(w * 16) * 64]);
        gload_lds16(kgb + (long)kp1 * 768 + swz * 8, &Kt[0][(w * 16 + 8) * 64]);
        gload_lds16(vgb + (long)d0 * 2048 + swz * 8, &Vt[0][(w * 16) * 64]);
        gload_lds16(vgb + (long)d1 * 2048 + swz * 8, &Vt[0][(w * 16 + 8) * 64]);
    }

    for (int it = 0; it < 32; it++) {
        const int cur = it & 1;
        __syncthreads();
        if (it < 31) {
            const int nxt = cur ^ 1, s0 = (it + 1) * 64;
            gload_lds16(kgb + (long)(s0 + kp0) * 768 + swz * 8, &Kt[nxt][(w * 16) * 64]);
            gload_lds16(kgb + (long)(s0 + kp1) * 768 + swz * 8, &Kt[nxt][(w * 16 + 8) * 64]);
            gload_lds16(vgb + (long)d0 * 2048 + s0 + swz * 8, &Vt[nxt][(w * 16) * 64]);
            gload_lds16(vgb + (long)d1 * 2048 + s0 + swz * 8, &Vt[nxt][(w * 16 + 8) * 64]);
        }

        const short* Kb = &Kt[cur][0];
        const short* Vb = &Vt[cur][0];

        // QK^T swapped: sv[ss][r] = S[k = 32*(ss>>1)+8*qr+4*(ss&1)+r][q=lc]
        floatx4 sv[4];
        __builtin_amdgcn_s_setprio(1);
#pragma unroll
        for (int ss = 0; ss < 4; ss++) {
            const short* kr = Kb + (ss * 16 + lc) * 64;
            short8 b0 = *(const short8*)(kr + ((qr ^ x7) << 3));
            short8 b1 = *(const short8*)(kr + (((4 + qr) ^ x7) << 3));
            floatx4 t = (floatx4){0.f, 0.f, 0.f, 0.f};
            t = __builtin_amdgcn_mfma_f32_16x16x32_bf16(b0, aq0, t, 0, 0, 0);
            t = __builtin_amdgcn_mfma_f32_16x16x32_bf16(b1, aq1, t, 0, 0, 0);
            sv[ss] = t;
        }
        __builtin_amdgcn_s_setprio(0);

        // lane-local softmax: p = exp2(s*0.125*log2e), pack to bf16 pairs
        float p[4][4];
#pragma unroll
        for (int ss = 0; ss < 4; ss++)
#pragma unroll
            for (int r = 0; r < 4; r++)
                p[ss][r] = __builtin_amdgcn_exp2f(sv[ss][r] * 0.18033688f);
#pragma unroll
        for (int ss = 0; ss < 4; ss++)
            lsum += (p[ss][0] + p[ss][1]) + (p[ss][2] + p[ss][3]);

        intx4 i0, i1;
        i0[0] = (int)cvt_pk_bf16(p[0][0], p[0][1]);
        i0[1] = (int)cvt_pk_bf16(p[0][2], p[0][3]);
        i0[2] = (int)cvt_pk_bf16(p[1][0], p[1][1]);
        i0[3] = (int)cvt_pk_bf16(p[1][2], p[1][3]);
        i1[0] = (int)cvt_pk_bf16(p[2][0], p[2][1]);
        i1[1] = (int)cvt_pk_bf16(p[2][2], p[2][3]);
        i1[2] = (int)cvt_pk_bf16(p[3][0], p[3][1]);
        i1[3] = (int)cvt_pk_bf16(p[3][2], p[3][3]);
        const short8 ap0 = __builtin_bit_cast(short8, i0);   // k = 8qr..8qr+7
        const short8 ap1 = __builtin_bit_cast(short8, i1);   // k = 32+8qr..+7

        __builtin_amdgcn_s_setprio(1);
#pragma unroll
        for (int dc = 0; dc < 4; dc++) {
            const short* vr = Vb + (dc * 16 + lc) * 64;
            short8 bv0 = *(const short8*)(vr + ((qr ^ x7) << 3));
            short8 bv1 = *(const short8*)(vr + (((4 + qr) ^ x7) << 3));
            cacc[dc] = __builtin_amdgcn_mfma_f32_16x16x32_bf16(ap0, bv0, cacc[dc], 0, 0, 0);
            cacc[dc] = __builtin_amdgcn_mfma_f32_16x16x32_bf16(ap1, bv1, cacc[dc], 0, 0, 0);
        }
        __builtin_amdgcn_s_setprio(0);
    }

    // l reduce: combine qr-group partials; lane qr*4+r then has q-row lc total
    lsum += __shfl_xor(lsum, 16);
    lsum += __shfl_xor(lsum, 32);
    float linv[4];
#pragma unroll
    for (int r = 0; r < 4; r++)
        linv[r] = 1.f / __shfl(lsum, qr * 4 + r);   // lane qr*4+r has lc==q

    short* cp = ctx + ((long)bg * 512 + tile * 64 + w * 16) * 768 + h * 64;
#pragma unroll
    for (int dc = 0; dc < 4; dc++)
#pragma unroll
        for (int r = 0; r < 4; r++)
            cp[(qr * 4 + r) * 768 + dc * 16 + lc] = f2bf(cacc[dc][r] * linv[r]);
}

// ---------------------------------------------------------------------------
extern "C" void kernel_launch(void* const* d_in, const int* in_sizes, int n_in,
                              void* d_out, int out_size, void* d_ws, size_t ws_size,
                              hipStream_t stream) {
    const float* query = (const float*)d_in[0];
    const float* key   = (const float*)d_in[1];
    const float* value = (const float*)d_in[2];
    const float* Wqg = (const float*)d_in[3];  const float* bqg = (const float*)d_in[4];
    const float* Wk  = (const float*)d_in[5];  const float* bk  = (const float*)d_in[6];
    const float* Wv  = (const float*)d_in[7];  const float* bv  = (const float*)d_in[8];
    const float* Wq_in = (const float*)d_in[9];  const float* bq_in = (const float*)d_in[10];
    const float* Wk_in = (const float*)d_in[11]; const float* bk_in = (const float*)d_in[12];
    const float* Wv_in = (const float*)d_in[13]; const float* bv_in = (const float*)d_in[14];
    const float* Wout  = (const float*)d_in[15]; const float* bout  = (const float*)d_in[16];
    float* out = (float*)d_out;

    // workspace (shorts), ~98 MB:
    short* ws     = (short*)d_ws;
    short* Wbf    = ws;                  // [0, 11206656)
    short* q_proj = ws + 11206656L;      // q | k | v, 3 x 3145728
    short* k_proj = ws + 14352384L;
    short* v_proj = ws + 17498112L;
    short* qiB    = ws + 20643840L;      // 3145728
    short* vtB    = ws + 23789568L;      // 12582912
    short* kiB    = ws + 36372480L;      // 12582912, end 48955392
    short* ctxB   = ws + 11206656L;      // aliases q-slice (dead after mid_gemm2)

    dim3 blk(256);

    cast_w<<<dim3(5472), blk, 0, stream>>>(
        Wqg, Wk, Wv, Wq_in, Wk_in, Wv_in, Wout, Wbf);

    qkv_gemm<<<dim3(576), blk, 0, stream>>>(
        query, key, value, Wbf, bqg, bk, bv, q_proj);

    mid_gemm2<<<dim3(432), dim3(512), 0, stream>>>(
        k_proj, v_proj, q_proj, Wbf, bq_in, bk_in, bv_in, kiB, vtB, qiB);

    attn_kernel<<<dim3(768), blk, 0, stream>>>(qiB, kiB, vtB, ctxB);

    out_gemm<<<dim3(192), blk, 65536, stream>>>(ctxB, Wbf, bout, out);
}

// Round 10
// 288.369 us; speedup vs baseline: 1.0810x; 1.0153x over previous
//
#include <hip/hip_runtime.h>
#include <hip/hip_bf16.h>

// GroupQueryAttention: B=2,S=2048,E=768,H=12,G=4,D=64,T=512
// R18 = R13 (banked best, 289.8us) with ONE change: mid_gemm2's
//      __launch_bounds__(512,2) -> (512,1). The "2" requested 2 blocks/CU,
//      impossible at 128KiB LDS/block; its only effect was capping the
//      register allocator at <=128 VGPR (observed 108) for an occupancy
//      that can't exist. At the true 1 block/CU the allocator may use the
//      full budget for deeper scheduling (G1/G6). qkv's R17 dbuf REVERTED
//      (+3us, neutral-negative); single-buffered R13 core restored.

typedef __attribute__((ext_vector_type(8))) short short8;
typedef __attribute__((ext_vector_type(4))) float floatx4;
typedef __attribute__((ext_vector_type(4))) int intx4;

static __device__ __forceinline__ short f2bf(float f) {
    __bf16 b = (__bf16)f;              // fptrunc RNE -> HW cvt
    return __builtin_bit_cast(short, b);
}
static __device__ __forceinline__ short8 f8_to_bf8(floatx4 f0, floatx4 f1) {
    short8 s;
    s[0]=f2bf(f0[0]); s[1]=f2bf(f0[1]); s[2]=f2bf(f0[2]); s[3]=f2bf(f0[3]);
    s[4]=f2bf(f1[0]); s[5]=f2bf(f1[1]); s[6]=f2bf(f1[2]); s[7]=f2bf(f1[3]);
    return s;
}
static __device__ __forceinline__ unsigned cvt_pk_bf16(float a, float b) {
    unsigned r;                        // D[15:0]=bf16(a), D[31:16]=bf16(b)
    asm("v_cvt_pk_bf16_f32 %0, %1, %2" : "=v"(r) : "v"(a), "v"(b));
    return r;
}
static __device__ __forceinline__ void gload_lds16(const short* g, short* l) {
    __builtin_amdgcn_global_load_lds(
        (const __attribute__((address_space(1))) unsigned int*)g,
        (__attribute__((address_space(3))) unsigned int*)l, 16, 0, 0);
}

// ---------------------------------------------------------------------------
// weights fp32->bf16 (7 tensors, 19*768^2 elems contiguous dst)
// ---------------------------------------------------------------------------
__global__ __launch_bounds__(256) void cast_w(
    const float* a0, const float* a1, const float* a2, const float* a3,
    const float* a4, const float* a5, const float* a6, short* dst)
{
    const long U = 589824L;
    const float* ptrs[7] = {a0,a1,a2,a3,a4,a5,a6};
    const long starts[8] = {0, U, 2*U, 3*U, 7*U, 11*U, 15*U, 19*U};
    long i = (long)blockIdx.x * 2048 + (long)threadIdx.x * 8;
    int t = 0;
    while (t < 6 && i >= starts[t + 1]) t++;
    const float* s = ptrs[t] + (i - starts[t]);
    floatx4 f0 = *(const floatx4*)s;
    floatx4 f1 = *(const floatx4*)(s + 4);
    *(short8*)(dst + i) = f8_to_bf8(f0, f1);
}

// ---------------------------------------------------------------------------
// 128x128 MFMA core pieces. C/D layout: col=lane&15, row=quad*4+reg.
// ---------------------------------------------------------------------------
#define GEMM_LANE_VARS                                                        \
    const int tid = threadIdx.x, lane = tid & 63, w = tid >> 6;               \
    const int wm = w & 1, wn = w >> 1;                                        \
    const int qr = lane >> 4, lc = lane & 15, x7 = lc & 7;                    \
    const int srow = tid >> 3, schunk = tid & 7, sx = srow & 7;

template<int CMODE, int BIAS_MODE>
static __device__ __forceinline__ void gemm_epilogue(
    floatx4 (&acc)[4][4], const float* bp, void* Cv, int ldc, int bm, int bn,
    int wm, int wn, int qr, int lc)
{
#pragma unroll
    for (int ni = 0; ni < 4; ni++) {
        const int gcol = bn * 128 + wn * 64 + ni * 16 + lc;
        const float bcol = (BIAS_MODE == 0) ? bp[gcol] : 0.f;
#pragma unroll
        for (int mi = 0; mi < 4; mi++) {
#pragma unroll
            for (int r = 0; r < 4; r++) {
                const int grow = bm * 128 + wm * 64 + mi * 16 + qr * 4 + r;
                const float bb = (BIAS_MODE == 1) ? bp[grow] : bcol;
                const float v = acc[mi][ni][r] + bb;
                if (CMODE == 0)
                    ((short*)Cv)[(long)grow * ldc + gcol] = f2bf(v);
                else
                    ((float*)Cv)[(long)grow * ldc + gcol] = v;
            }
        }
    }
}

static __device__ __forceinline__ void gemm_mfma_step(
    floatx4 (&acc)[4][4], const short* Ac, const short* Bc,
    int wm, int wn, int qr, int lc, int x7)
{
#pragma unroll
    for (int ks = 0; ks < 64; ks += 32) {
        const int c0 = (ks >> 3) + qr;
        const int slot = ((c0 ^ x7) << 3);
        short8 af[4], bfr[4];
#pragma unroll
        for (int mi = 0; mi < 4; mi++)
            af[mi] = *(const short8*)&Ac[(wm * 64 + mi * 16 + lc) * 64 + slot];
#pragma unroll
        for (int ni = 0; ni < 4; ni++)
            bfr[ni] = *(const short8*)&Bc[(wn * 64 + ni * 16 + lc) * 64 + slot];
#pragma unroll
        for (int mi = 0; mi < 4; mi++)
#pragma unroll
            for (int ni = 0; ni < 4; ni++)
                acc[mi][ni] = __builtin_amdgcn_mfma_f32_16x16x32_bf16(
                    af[mi], bfr[ni], acc[mi][ni], 0, 0, 0);
    }
}

// ---------------------------------------------------------------------------
// Double-buffered 128x128 bf16 core (used by out_gemm).
// ---------------------------------------------------------------------------
template<int CMODE, int BIAS_MODE>
static __device__ __forceinline__ void gemm_core_db(
    const short* __restrict__ A, const short* __restrict__ Wb,
    const float* __restrict__ bp, void* __restrict__ Cv,
    int lda, int ldc, int bm, int bn, short* As, short* Bs)
{
    GEMM_LANE_VARS
    const short* Ab = A + (long)(bm * 128) * lda;
    const short* Wt = Wb + (long)(bn * 128) * 768;
    const int gch = ((schunk ^ sx) << 3);

    floatx4 acc[4][4];
#pragma unroll
    for (int mi = 0; mi < 4; mi++)
#pragma unroll
        for (int ni = 0; ni < 4; ni++) acc[mi][ni] = (floatx4){0.f, 0.f, 0.f, 0.f};

#pragma unroll
    for (int p = 0; p < 4; p++) {
        gload_lds16(Ab + (long)(p * 32 + srow) * lda + gch, &As[(p * 32 + w * 8) * 64]);
        gload_lds16(Wt + (long)(p * 32 + srow) * 768 + gch, &Bs[(p * 32 + w * 8) * 64]);
    }

    for (int kk = 0; kk < 12; kk++) {
        __syncthreads();   // drains loads for tile kk (issued last iter); fences buf reuse
        if (kk < 11) {
            const int k1 = (kk + 1) * 64;
            const int nb = ((kk + 1) & 1) * 8192;
#pragma unroll
            for (int p = 0; p < 4; p++) {
                gload_lds16(Ab + (long)(p * 32 + srow) * lda + k1 + gch,
                            &As[nb + (p * 32 + w * 8) * 64]);
                gload_lds16(Wt + (long)(p * 32 + srow) * 768 + k1 + gch,
                            &Bs[nb + (p * 32 + w * 8) * 64]);
            }
        }
        gemm_mfma_step(acc, As + (kk & 1) * 8192, Bs + (kk & 1) * 8192,
                       wm, wn, qr, lc, x7);
    }
    gemm_epilogue<CMODE, BIAS_MODE>(acc, bp, Cv, ldc, bm, bn, wm, wn, qr, lc);
}

// ---------------------------------------------------------------------------
// Single-buffered core for fp32 A (qkv only) -- R13 version restored.
// ---------------------------------------------------------------------------
template<int CMODE, int BIAS_MODE>
static __device__ __forceinline__ void gemm_core_f32(
    const float* __restrict__ A, const short* __restrict__ Wb,
    const float* __restrict__ bp, void* __restrict__ Cv,
    int lda, int ldc, int bm, int bn, short* As, short* Bs)
{
    GEMM_LANE_VARS
    const short* Wt = Wb + (long)(bn * 128) * 768;

    floatx4 acc[4][4];
#pragma unroll
    for (int mi = 0; mi < 4; mi++)
#pragma unroll
        for (int ni = 0; ni < 4; ni++) acc[mi][ni] = (floatx4){0.f, 0.f, 0.f, 0.f};

    for (int k0 = 0; k0 < 768; k0 += 64) {
        __syncthreads();
#pragma unroll
        for (int p = 0; p < 4; p++) {
            const int row = p * 32 + srow;
            const float* ap = A + (long)(bm * 128 + row) * lda + k0 + schunk * 8;
            floatx4 f0 = *(const floatx4*)ap;
            floatx4 f1 = *(const floatx4*)(ap + 4);
            *(short8*)&As[row * 64 + ((schunk ^ sx) << 3)] = f8_to_bf8(f0, f1);
            gload_lds16(Wt + (long)row * 768 + k0 + ((schunk ^ sx) << 3),
                        &Bs[(p * 32 + w * 8) * 64]);
        }
        __syncthreads();
        gemm_mfma_step(acc, As, Bs, wm, wn, qr, lc, x7);
    }
    gemm_epilogue<CMODE, BIAS_MODE>(acc, bp, Cv, ldc, bm, bn, wm, wn, qr, lc);
}

// qkv projections: grid (576). XCD k owns bm in [4k,4k+4); order bm->y->bn.
__global__ __launch_bounds__(256) void qkv_gemm(
    const float* q, const float* k, const float* v, const short* Wbf,
    const float* bq, const float* bk, const float* bv, short* outp)
{
    __shared__ short As[128 * 64];
    __shared__ short Bs[128 * 64];
    const int xcd = blockIdx.x & 7, slot = blockIdx.x >> 3;   // slot 0..71
    const int bm = xcd * 4 + slot / 18;
    const int rem = slot % 18, y = rem / 6, bn = rem % 6;
    const float* A    = (y == 0) ? q  : (y == 1) ? k  : v;
    const float* bias = (y == 0) ? bq : (y == 1) ? bk : bv;
    gemm_core_f32<0, 0>(A, Wbf + (long)y * 589824, bias, outp + (long)y * 3145728,
                        768, 768, bm, bn, As, Bs);
}

// ---------------------------------------------------------------------------
// 256x256-tile 8-wave 8-phase bf16 GEMM core, per-phase staging interleave
// (R10 version -- best measured). BK=64, 12 K-tiles, 2 LDS slots (dbuf).
// ---------------------------------------------------------------------------
template<int BIAS_MODE>
static __device__ __forceinline__ void gemm256_core(
    const short* __restrict__ A, const short* __restrict__ B,
    const float* __restrict__ bias, short* __restrict__ C,
    int lda, int ldc, int bm, int bn, short* As, short* Bs)
{
    const int tid = threadIdx.x, lane = tid & 63, w = tid >> 6;   // 8 waves
    const int wm = w & 1, wn = w >> 1;                            // 2 x 4
    const int qr = lane >> 4, lc = lane & 15, x7 = lc & 7;
    const int srow = tid >> 3, schunk = tid & 7;                  // srow 0..63
    const int gch = ((schunk ^ (srow & 7)) << 3);

    const short* Ab = A + (long)(bm * 256) * lda;
    const short* Bb = B + (long)(bn * 256) * 768;

    floatx4 acc[8][4];
#pragma unroll
    for (int i = 0; i < 8; i++)
#pragma unroll
        for (int j = 0; j < 4; j++) acc[i][j] = (floatx4){0.f, 0.f, 0.f, 0.f};

    // prologue: stage K-tile 0 -> slot 0 (8 gload_lds / thread, burst)
#pragma unroll
    for (int r = 0; r < 256; r += 64) {
        gload_lds16(Ab + (long)(r + srow) * lda + gch, As + (r + w * 8) * 64);
        gload_lds16(Bb + (long)(r + srow) * 768 + gch, Bs + (r + w * 8) * 64);
    }

#pragma unroll 1
    for (int kt = 0; kt < 12; ++kt) {
        const int s = kt & 1;
        const short* Ac = As + s * 16384;
        const short* Bc = Bs + s * 16384;
        short* Ad = As + (1 - s) * 16384;
        short* Bd = Bs + (1 - s) * 16384;
        const int koff = (kt + 1) * 64;

        // publish tile kt's staging (all waves), then fence slot reuse
        asm volatile("s_waitcnt vmcnt(0)" ::: "memory");
        __builtin_amdgcn_s_barrier();

        short8 af[4][2], bfr[2][2];
#pragma unroll
        for (int ph = 0; ph < 4; ++ph) {
            const int mh = ph >> 1, nh = ph & 1;
            // ds-load this phase's fragments (slot s)
            if (nh == 0) {   // A half-frags live for two phases
#pragma unroll
                for (int mi = 0; mi < 4; mi++)
#pragma unroll
                    for (int ks = 0; ks < 2; ks++)
                        af[mi][ks] = *(const short8*)&Ac[
                            (wm * 128 + (mh * 4 + mi) * 16 + lc) * 64 +
                            ((((ks << 2) + qr) ^ x7) << 3)];
            }
#pragma unroll
            for (int ni = 0; ni < 2; ni++)
#pragma unroll
                for (int ks = 0; ks < 2; ks++)
                    bfr[ni][ks] = *(const short8*)&Bc[
                        (wn * 64 + (nh * 2 + ni) * 16 + lc) * 64 +
                        ((((ks << 2) + qr) ^ x7) << 3)];
            // stage quarter ph of tile kt+1 -> slot 1-s (fine interleave)
            if (kt < 11) {
                const int r = ph * 64;
                gload_lds16(Ab + (long)(r + srow) * lda + koff + gch,
                            Ad + (r + w * 8) * 64);
                gload_lds16(Bb + (long)(r + srow) * 768 + koff + gch,
                            Bd + (r + w * 8) * 64);
            }
            __builtin_amdgcn_s_barrier();
            asm volatile("s_waitcnt lgkmcnt(0)" ::: "memory");
            __builtin_amdgcn_sched_barrier(0);
            __builtin_amdgcn_s_setprio(1);
#pragma unroll
            for (int ks = 0; ks < 2; ks++)
#pragma unroll
                for (int mi = 0; mi < 4; mi++)
#pragma unroll
                    for (int ni = 0; ni < 2; ni++)
                        acc[mh * 4 + mi][nh * 2 + ni] =
                            __builtin_amdgcn_mfma_f32_16x16x32_bf16(
                                af[mi][ks], bfr[ni][ks],
                                acc[mh * 4 + mi][nh * 2 + ni], 0, 0, 0);
            __builtin_amdgcn_s_setprio(0);
            __builtin_amdgcn_sched_barrier(0);
            __builtin_amdgcn_s_barrier();
        }
    }

    // epilogue
#pragma unroll
    for (int ni = 0; ni < 4; ni++) {
        const int gcol = bn * 256 + wn * 64 + ni * 16 + lc;
        const float bcol = (BIAS_MODE == 0) ? bias[gcol] : 0.f;
#pragma unroll
        for (int mi = 0; mi < 8; mi++) {
#pragma unroll
            for (int r = 0; r < 4; r++) {
                const int grow = bm * 256 + wm * 128 + mi * 16 + qr * 4 + r;
                const float bb = (BIAS_MODE == 1) ? bias[grow] : bcol;
                C[(long)grow * ldc + gcol] = f2bf(acc[mi][ni][r] + bb);
            }
        }
    }
}

// mid GEMMs fused: grid (432) x 512 thr, 128 KiB static LDS, 1 block/CU.
// launch_bounds (512,1): LDS already limits to 1 block/CU; requesting 2
// only capped the register allocator (R18 change).
__global__ __launch_bounds__(512, 1) void mid_gemm2(
    const short* kproj, const short* vproj, const short* qproj, const short* Wbf,
    const float* bq_in, const float* bk_in, const float* bv_in,
    short* kiB, short* vtB, short* qiB)
{
    __shared__ short As[2 * 16384];   // 2 slots x 256 rows x 64 (64 KiB)
    __shared__ short Bs[2 * 16384];   // 64 KiB
    const int xcd = blockIdx.x & 7, slot = blockIdx.x >> 3;   // slot 0..53
    const int z = xcd, b = z >> 2, g = z & 3;
    if (slot < 24) {          // ki[s,f] = kproj @ Wk_in^T : M=2048, N=768
        gemm256_core<0>(kproj + (long)b * 1572864, Wbf + (long)(7 + g) * 589824,
                        bk_in + g * 768, kiB + (long)z * 1572864,
                        768, 768, slot / 3, slot % 3, As, Bs);
    } else if (slot < 48) {   // vt[f,s] = Wv_in @ vproj^T : M=768, N=2048
        const int s2 = slot - 24;
        gemm256_core<1>(Wbf + (long)(11 + g) * 589824, vproj + (long)b * 1572864,
                        bv_in + g * 768, vtB + (long)z * 1572864,
                        768, 2048, s2 / 8, s2 % 8, As, Bs);
    } else {                  // qi: M=512, interleaved gather (token = t*4+g)
        const int s3 = slot - 48;
        gemm256_core<0>(qproj + (long)b * 1572864 + g * 768, Wbf + (long)(3 + g) * 589824,
                        bq_in + g * 768, qiB + (long)z * 393216,
                        3072, 768, s3 / 3, s3 % 3, As, Bs);
    }
}

// out projection: grid (192), dyn LDS 64 KB. fp32 C scattered (ldc=3072).
__global__ __launch_bounds__(256) void out_gemm(
    const short* ctxB, const short* Wbf, const float* bout, float* out)
{
    extern __shared__ short sm[];
    short* As = sm;
    short* Bs = sm + 16384;
    const int xcd = blockIdx.x & 7, slot = blockIdx.x >> 3;   // slot 0..23
    const int z = xcd, b = z >> 2, g = z & 3;
    gemm_core_db<2, 0>(ctxB + (long)z * 393216, Wbf + (long)(15 + g) * 589824,
                       bout + g * 768, out + (long)b * 1572864 + g * 768,
                       768, 3072, slot / 6, slot % 6, As, Bs);
}

// ---------------------------------------------------------------------------
// Flash attention, lane-local softmax (R13 -- banked best). 1 WG = 64 q-rows
// of one (b,g,h). QK^T swapped (A=K, B=Q): lane (qr,lc) owns P[k][q=lc].
// K rows staged PERMUTED so lane-owned k's == PV A-frag k's:
//   dest row d holds global row kperm(d) = 32*d5 + 8*((d>>2)&3) + 4*d4 + (d&3)
//   => tile ss, reg r: k = 32*(ss>>1) + 8*qr + 4*(ss&1) + r
// P never touches LDS; l-sum = per-lane f32, reduced once at the end.
// ---------------------------------------------------------------------------
__global__ __launch_bounds__(256) void attn_kernel(
    const short* __restrict__ qi, const short* __restrict__ ki,
    const short* __restrict__ vt, short* __restrict__ ctx)
{
    __shared__ short Kt[2][64 * 64];
    __shared__ short Vt[2][64 * 64];

    const int tid = threadIdx.x, lane = tid & 63, w = tid >> 6;
    const int qr = lane >> 4, lc = lane & 15, x7 = lc & 7;
    const int headid = blockIdx.x % 96;
    const int tile = blockIdx.x / 96;
    const int h = headid % 12, bg = headid / 12;

    const short* qp = qi + ((long)bg * 512 + tile * 64 + w * 16 + lc) * 768 + h * 64 + qr * 8;
    const short8 aq0 = *(const short8*)qp;
    const short8 aq1 = *(const short8*)(qp + 32);

    floatx4 cacc[4];
    float lsum = 0.f;
#pragma unroll
    for (int dc = 0; dc < 4; dc++) cacc[dc] = (floatx4){0.f, 0.f, 0.f, 0.f};

    const int srow = lane >> 3, schk = lane & 7, swz = schk ^ srow;
    const short* kgb = ki + ((long)bg * 2048) * 768 + h * 64;
    const short* vgb = vt + ((long)(bg * 768 + h * 64)) * 2048;

    // K-row permutation (loop-invariant): dest rows d0/d1 for inst 0/1
#define KPERM(d) ((((d) >> 5) & 1) * 32 + (((d) >> 2) & 3) * 8 + (((d) >> 4) & 1) * 4 + ((d) & 3))
    const int d0 = w * 16 + srow, d1 = d0 + 8;
    const int kp0 = KPERM(d0), kp1 = KPERM(d1);
#undef KPERM

    {   // prologue staging (K permuted, V linear)
        gload_lds16(kgb + (long)kp0 * 768 + swz * 8, &Kt[0][(w * 16) * 64]);
        gload_lds16(kgb + (long)kp1 * 768 + swz * 8, &Kt[0][(w * 16 + 8) * 64]);
        gload_lds16(vgb + (long)d0 * 2048 + swz * 8, &Vt[0][(w * 16) * 64]);
        gload_lds16(vgb + (long)d1 * 2048 + swz * 8, &Vt[0][(w * 16 + 8) * 64]);
    }

    for (int it = 0; it < 32; it++) {
        const int cur = it & 1;
        __syncthreads();
        if (it < 31) {
            const int nxt = cur ^ 1, s0 = (it + 1) * 64;
            gload_lds16(kgb + (long)(s0 + kp0) * 768 + swz * 8, &Kt[nxt][(w * 16) * 64]);
            gload_lds16(kgb + (long)(s0 + kp1) * 768 + swz * 8, &Kt[nxt][(w * 16 + 8) * 64]);
            gload_lds16(vgb + (long)d0 * 2048 + s0 + swz * 8, &Vt[nxt][(w * 16) * 64]);
            gload_lds16(vgb + (long)d1 * 2048 + s0 + swz * 8, &Vt[nxt][(w * 16 + 8) * 64]);
        }

        const short* Kb = &Kt[cur][0];
        const short* Vb = &Vt[cur][0];

        // QK^T swapped: sv[ss][r] = S[k = 32*(ss>>1)+8*qr+4*(ss&1)+r][q=lc]
        floatx4 sv[4];
        __builtin_amdgcn_s_setprio(1);
#pragma unroll
        for (int ss = 0; ss < 4; ss++) {
            const short* kr = Kb + (ss * 16 + lc) * 64;
            short8 b0 = *(const short8*)(kr + ((qr ^ x7) << 3));
            short8 b1 = *(const short8*)(kr + (((4 + qr) ^ x7) << 3));
            floatx4 t = (floatx4){0.f, 0.f, 0.f, 0.f};
            t = __builtin_amdgcn_mfma_f32_16x16x32_bf16(b0, aq0, t, 0, 0, 0);
            t = __builtin_amdgcn_mfma_f32_16x16x32_bf16(b1, aq1, t, 0, 0, 0);
            sv[ss] = t;
        }
        __builtin_amdgcn_s_setprio(0);

        // lane-local softmax: p = exp2(s*0.125*log2e), pack to bf16 pairs
        float p[4][4];
#pragma unroll
        for (int ss = 0; ss < 4; ss++)
#pragma unroll
            for (int r = 0; r < 4; r++)
                p[ss][r] = __builtin_amdgcn_exp2f(sv[ss][r] * 0.18033688f);
#pragma unroll
        for (int ss = 0; ss < 4; ss++)
            lsum += (p[ss][0] + p[ss][1]) + (p[ss][2] + p[ss][3]);

        intx4 i0, i1;
        i0[0] = (int)cvt_pk_bf16(p[0][0], p[0][1]);
        i0[1] = (int)cvt_pk_bf16(p[0][2], p[0][3]);
        i0[2] = (int)cvt_pk_bf16(p[1][0], p[1][1]);
        i0[3] = (int)cvt_pk_bf16(p[1][2], p[1][3]);
        i1[0] = (int)cvt_pk_bf16(p[2][0], p[2][1]);
        i1[1] = (int)cvt_pk_bf16(p[2][2], p[2][3]);
        i1[2] = (int)cvt_pk_bf16(p[3][0], p[3][1]);
        i1[3] = (int)cvt_pk_bf16(p[3][2], p[3][3]);
        const short8 ap0 = __builtin_bit_cast(short8, i0);   // k = 8qr..8qr+7
        const short8 ap1 = __builtin_bit_cast(short8, i1);   // k = 32+8qr..+7

        __builtin_amdgcn_s_setprio(1);
#pragma unroll
        for (int dc = 0; dc < 4; dc++) {
            const short* vr = Vb + (dc * 16 + lc) * 64;
            short8 bv0 = *(const short8*)(vr + ((qr ^ x7) << 3));
            short8 bv1 = *(const short8*)(vr + (((4 + qr) ^ x7) << 3));
            cacc[dc] = __builtin_amdgcn_mfma_f32_16x16x32_bf16(ap0, bv0, cacc[dc], 0, 0, 0);
            cacc[dc] = __builtin_amdgcn_mfma_f32_16x16x32_bf16(ap1, bv1, cacc[dc], 0, 0, 0);
        }
        __builtin_amdgcn_s_setprio(0);
    }

    // l reduce: combine qr-group partials; lane qr*4+r then has q-row lc total
    lsum += __shfl_xor(lsum, 16);
    lsum += __shfl_xor(lsum, 32);
    float linv[4];
#pragma unroll
    for (int r = 0; r < 4; r++)
        linv[r] = 1.f / __shfl(lsum, qr * 4 + r);   // lane qr*4+r has lc==q

    short* cp = ctx + ((long)bg * 512 + tile * 64 + w * 16) * 768 + h * 64;
#pragma unroll
    for (int dc = 0; dc < 4; dc++)
#pragma unroll
        for (int r = 0; r < 4; r++)
            cp[(qr * 4 + r) * 768 + dc * 16 + lc] = f2bf(cacc[dc][r] * linv[r]);
}

// ---------------------------------------------------------------------------
extern "C" void kernel_launch(void* const* d_in, const int* in_sizes, int n_in,
                              void* d_out, int out_size, void* d_ws, size_t ws_size,
                              hipStream_t stream) {
    const float* query = (const float*)d_in[0];
    const float* key   = (const float*)d_in[1];
    const float* value = (const float*)d_in[2];
    const float* Wqg = (const float*)d_in[3];  const float* bqg = (const float*)d_in[4];
    const float* Wk  = (const float*)d_in[5];  const float* bk  = (const float*)d_in[6];
    const float* Wv  = (const float*)d_in[7];  const float* bv  = (const float*)d_in[8];
    const float* Wq_in = (const float*)d_in[9];  const float* bq_in = (const float*)d_in[10];
    const float* Wk_in = (const float*)d_in[11]; const float* bk_in = (const float*)d_in[12];
    const float* Wv_in = (const float*)d_in[13]; const float* bv_in = (const float*)d_in[14];
    const float* Wout  = (const float*)d_in[15]; const float* bout  = (const float*)d_in[16];
    float* out = (float*)d_out;

    // workspace (shorts), ~98 MB:
    short* ws     = (short*)d_ws;
    short* Wbf    = ws;                  // [0, 11206656)
    short* q_proj = ws + 11206656L;      // q | k | v, 3 x 3145728
    short* k_proj = ws + 14352384L;
    short* v_proj = ws + 17498112L;
    short* qiB    = ws + 20643840L;      // 3145728
    short* vtB    = ws + 23789568L;      // 12582912
    short* kiB    = ws + 36372480L;      // 12582912, end 48955392
    short* ctxB   = ws + 11206656L;      // aliases q-slice (dead after mid_gemm2)

    dim3 blk(256);

    cast_w<<<dim3(5472), blk, 0, stream>>>(
        Wqg, Wk, Wv, Wq_in, Wk_in, Wv_in, Wout, Wbf);

    qkv_gemm<<<dim3(576), blk, 0, stream>>>(
        query, key, value, Wbf, bqg, bk, bv, q_proj);

    mid_gemm2<<<dim3(432), dim3(512), 0, stream>>>(
        k_proj, v_proj, q_proj, Wbf, bq_in, bk_in, bv_in, kiB, vtB, qiB);

    attn_kernel<<<dim3(768), blk, 0, stream>>>(qiB, kiB, vtB, ctxB);

    out_gemm<<<dim3(192), blk, 65536, stream>>>(ctxB, Wbf, bout, out);
}